// Round 9
// baseline (260.047 us; speedup 1.0000x reference)
//
#include <hip/hip_runtime.h>
#include <stdint.h>

#define B_ 4
#define L_ 4096
#define D_ 1024
#define C_ 2048
#define M_ (B_ * L_)  // 16384

typedef __attribute__((ext_vector_type(8))) short s16x8;
typedef __attribute__((ext_vector_type(4))) float fx4;
typedef __attribute__((ext_vector_type(4))) unsigned int ux4;
typedef unsigned short bfu;  // bf16 bits

__device__ __forceinline__ float bits2f(short s) {
  return __uint_as_float(((uint32_t)(unsigned short)s) << 16);
}
__device__ __forceinline__ bfu f2bf(float f) {
  uint32_t u = __float_as_uint(f);
  uint32_t r = (u + 0x7FFFu + ((u >> 16) & 1u)) >> 16;  // RNE
  return (bfu)r;
}

__device__ __forceinline__ void gload_lds16(const void* g, void* l) {
  __builtin_amdgcn_global_load_lds(
      (const __attribute__((address_space(1))) void*)g,
      (__attribute__((address_space(3))) void*)l, 16, 0, 0);
}

#define BAR() asm volatile("s_barrier" ::: "memory")
#define LGKM0() asm volatile("s_waitcnt lgkmcnt(0)" ::: "memory")
#define VMW23() asm volatile("s_waitcnt vmcnt(23)" ::: "memory")
#define VMW8() asm volatile("s_waitcnt vmcnt(8)" ::: "memory")
#define VMW4() asm volatile("s_waitcnt vmcnt(4)" ::: "memory")
#define VMW0() asm volatile("s_waitcnt vmcnt(0)" ::: "memory")

// ---------------- fp32 -> bf16 bulk convert ----------------
__global__ __launch_bounds__(256) void cvt_f32_bf16(const float* __restrict__ in,
                                                    bfu* __restrict__ out, int n8) {
  const int stride = gridDim.x * blockDim.x;
  for (int i = blockIdx.x * blockDim.x + threadIdx.x; i < n8; i += stride) {
    const size_t off = (size_t)i * 8;
    fx4 a = *(const fx4*)(in + off);
    fx4 b = *(const fx4*)(in + off + 4);
    s16x8 o;
#pragma unroll
    for (int j = 0; j < 4; j++) {
      o[j] = (short)f2bf(a[j]);
      o[j + 4] = (short)f2bf(b[j]);
    }
    *reinterpret_cast<s16x8*>(out + off) = o;
  }
}

// ---------------- transpose + fp32->bf16 convert: out[c][r] = in[r][c] ----------------
template <int R, int CC>
__global__ __launch_bounds__(256) void transpose_cvt(const float* __restrict__ in,
                                                     bfu* __restrict__ out) {
  __shared__ float tile[32][33];
  const int bx = blockIdx.x, by = blockIdx.y, tx = threadIdx.x;
  for (int j = threadIdx.y; j < 32; j += 8)
    tile[j][tx] = in[(size_t)(by * 32 + j) * CC + bx * 32 + tx];
  __syncthreads();
  for (int j = threadIdx.y; j < 32; j += 8)
    out[(size_t)(bx * 32 + j) * R + by * 32 + tx] = f2bf(tile[tx][j]);
}

// ---------------- conv weight pack: wtab[cp][0..3]=cw taps (2xbf16), [4]=cb pair ------
__global__ __launch_bounds__(256) void prep_cw(const float* __restrict__ cw,
                                               const float* __restrict__ cb,
                                               uint32_t* __restrict__ wtab) {
  const int c = blockIdx.x * 256 + threadIdx.x;  // ch-pair 0..1023
  uint32_t* o = wtab + c * 8;                    // 32 B stride (16B-aligned)
#pragma unroll
  for (int t4 = 0; t4 < 4; t4++)
    o[t4] = ((uint32_t)f2bf(cw[t4 * C_ + 2 * c + 1]) << 16) | f2bf(cw[t4 * C_ + 2 * c]);
  o[4] = ((uint32_t)f2bf(cb[2 * c + 1]) << 16) | f2bf(cb[2 * c]);
}

// =================== 256x256 8-phase GEMM pieces ===================
// LDS buffer (elements): A-kh0 @0, A-kh1 @8192, B-kh0 @16384, B-kh1 @24576;
// buf1 = +32768.  Rows are 64 B (32 bf16).  Swizzle involution (both sides):
// XOR bits 4-5 of the linear byte address with row bits 1-2.

template <int KD>
__device__ __forceinline__ void stage_half(const bfu* __restrict__ Mt, int r0, int kb,
                                           bfu* region, int t) {
#pragma unroll
  for (int h = 0; h < 2; h++) {
    const int u = t + h * 512;
    const int srow = u >> 2;
    const int sslot = (u & 3) ^ ((srow >> 1) & 3);
    gload_lds16(Mt + (size_t)(r0 + srow) * KD + kb + sslot * 8, region + u * 8);
  }
}

#define LF(bytoff) \
  (*reinterpret_cast<const s16x8*>(reinterpret_cast<const char*>(lds) + (bytoff)))

// ---------------- plain GEMM (GEMM1): R7 structure ----------------
template <int MM, int N, int KD, bool OUT_BF16>
__global__ __launch_bounds__(512, 2) void gemm256(const bfu* __restrict__ A,
                                                  const bfu* __restrict__ Bt,
                                                  const float* __restrict__ bias,
                                                  void* __restrict__ Cptr) {
  __shared__ bfu lds[2 * 4 * 8192];  // 128 KiB
  const int t = threadIdx.x;
  const int lane = t & 63, wid = t >> 6;
  const int wr = wid >> 2, wc = wid & 3;
  const int lr = lane & 15, lg = lane >> 4;
  const int cpx = gridDim.x >> 3;
  const int li = (blockIdx.x & 7) * cpx + (blockIdx.x >> 3);
  const int row0 = (li % (MM / 256)) * 256;
  const int col0 = (li / (MM / 256)) * 256;
  constexpr int ntk = KD / 64;
  const int abase = ((wr * 128 + lr) * 64 + lg * 16) ^ (((lr >> 1) & 3) << 4);
  const int bbase = ((wc * 64 + lr) * 64 + lg * 16) ^ (((lr >> 1) & 3) << 4);

  fx4 acc[8][4] = {};

  stage_half<KD>(A, row0, 0, lds + 0, t);
  stage_half<KD>(Bt, col0, 0, lds + 16384, t);
  stage_half<KD>(A, row0, 32, lds + 8192, t);
  stage_half<KD>(Bt, col0, 32, lds + 24576, t);
  stage_half<KD>(A, row0, 64, lds + 32768 + 0, t);
  stage_half<KD>(Bt, col0, 64, lds + 32768 + 16384, t);
  VMW8();
  BAR();

  for (int tau = 0; tau < ntk; ++tau) {
    const int cbb = (tau & 1) ? 65536 : 0;
    bfu* nb_ = (tau & 1) ? lds : lds + 32768;
    s16x8 af[4], bf4[4];

#pragma unroll
    for (int m = 0; m < 4; m++) af[m] = LF(cbb + abase + m * 1024);
#pragma unroll
    for (int n = 0; n < 4; n++) bf4[n] = LF(cbb + 32768 + bbase + n * 1024);
    if (tau + 1 < ntk) stage_half<KD>(A, row0, (tau + 1) * 64 + 32, nb_ + 8192, t);
    BAR();
    LGKM0();
    __builtin_amdgcn_s_setprio(1);
#pragma unroll
    for (int m = 0; m < 4; m++)
#pragma unroll
      for (int n = 0; n < 4; n++)
        acc[m][n] = __builtin_amdgcn_mfma_f32_16x16x32_bf16(af[m], bf4[n], acc[m][n], 0, 0, 0);
    __builtin_amdgcn_s_setprio(0);
    BAR();

#pragma unroll
    for (int m = 0; m < 4; m++) af[m] = LF(cbb + abase + 4096 + m * 1024);
    if (tau + 1 < ntk) stage_half<KD>(Bt, col0, (tau + 1) * 64 + 32, nb_ + 24576, t);
    BAR();
    LGKM0();
    __builtin_amdgcn_s_setprio(1);
#pragma unroll
    for (int m = 0; m < 4; m++)
#pragma unroll
      for (int n = 0; n < 4; n++)
        acc[m + 4][n] = __builtin_amdgcn_mfma_f32_16x16x32_bf16(af[m], bf4[n], acc[m + 4][n], 0, 0, 0);
    __builtin_amdgcn_s_setprio(0);
    if (tau < ntk - 1) VMW8();
    else VMW0();
    BAR();

#pragma unroll
    for (int m = 0; m < 4; m++) af[m] = LF(cbb + 16384 + abase + m * 1024);
#pragma unroll
    for (int n = 0; n < 4; n++) bf4[n] = LF(cbb + 49152 + bbase + n * 1024);
    if (tau + 2 < ntk) stage_half<KD>(A, row0, (tau + 2) * 64, lds + (cbb >> 1), t);
    BAR();
    LGKM0();
    __builtin_amdgcn_s_setprio(1);
#pragma unroll
    for (int m = 0; m < 4; m++)
#pragma unroll
      for (int n = 0; n < 4; n++)
        acc[m][n] = __builtin_amdgcn_mfma_f32_16x16x32_bf16(af[m], bf4[n], acc[m][n], 0, 0, 0);
    __builtin_amdgcn_s_setprio(0);
    BAR();

#pragma unroll
    for (int m = 0; m < 4; m++) af[m] = LF(cbb + 16384 + abase + 4096 + m * 1024);
    if (tau + 2 < ntk) stage_half<KD>(Bt, col0, (tau + 2) * 64, lds + (cbb >> 1) + 16384, t);
    BAR();
    LGKM0();
    __builtin_amdgcn_s_setprio(1);
#pragma unroll
    for (int m = 0; m < 4; m++)
#pragma unroll
      for (int n = 0; n < 4; n++)
        acc[m + 4][n] = __builtin_amdgcn_mfma_f32_16x16x32_bf16(af[m], bf4[n], acc[m + 4][n], 0, 0, 0);
    __builtin_amdgcn_s_setprio(0);
    if (tau < ntk - 2) VMW8();
    else if (tau == ntk - 2) VMW4();
    BAR();
  }

  float bv[4];
#pragma unroll
  for (int n = 0; n < 4; n++) bv[n] = bias[col0 + wc * 64 + n * 16 + lr];
#pragma unroll
  for (int m = 0; m < 8; m++)
#pragma unroll
    for (int n = 0; n < 4; n++)
#pragma unroll
      for (int r = 0; r < 4; r++) {
        const int row = row0 + wr * 128 + m * 16 + lg * 4 + r;
        const int col = col0 + wc * 64 + n * 16 + lr;
        const float v = acc[m][n][r] + bv[n];
        if constexpr (OUT_BF16)
          ((bfu*)Cptr)[(size_t)row * N + col] = f2bf(v);
        else
          ((float*)Cptr)[(size_t)row * N + col] = v;
      }
}

// ---------------- fused GEMM2: out = conv(xe) @ W_cmp + b_cmp ----------------
// A-staging computes y on the fly: thread (rg=lane>>2, cp=wid*4+(lane&3)) owns
// rows [row0+rg*16, +16) x ch-pair cp of each K-tile.  Batch = 19 xe dwords +
// packed weights; issued at P4-end for tile tau+2; conv+ds_write at (tau+1).P3
// (kh0, waves 0-3) / P4 (kh1, waves 4-7), post-barrier.
struct Batch {
  uint32_t x[19];
  ux4 w;
  uint32_t cb;
};

__device__ __forceinline__ void batch_load(Batch& b, const bfu* __restrict__ xe,
                                           const uint32_t* __restrict__ wtab,
                                           int row0, int rg, int cp, int tile) {
  const bfu* p = xe + (size_t)(row0 + rg * 16 - 3) * C_ + tile * 64 + cp * 2;
#pragma unroll
  for (int j = 0; j < 19; j++)
    b.x[j] = *reinterpret_cast<const uint32_t*>(p + (size_t)j * C_);
  const uint32_t* wp = wtab + (tile * 32 + cp) * 8;
  b.w = *reinterpret_cast<const ux4*>(wp);
  b.cb = wp[4];
}

__device__ __forceinline__ void conv_write(bfu* nbase, const Batch& b, int rg, int cp,
                                           bool zero_head) {
  bfu* region = nbase + ((cp & 16) ? 8192 : 0);
  char* vrow = reinterpret_cast<char*>(region) + rg * 1024;  // rg*16 rows x 64 B
  const int colb = (cp & 15) * 4;                            // column byte (bits 2-5)
  float wl[4], wh[4];
#pragma unroll
  for (int t4 = 0; t4 < 4; t4++) {
    const uint32_t wv = b.w[t4];
    wl[t4] = bits2f((short)(wv & 0xffffu));
    wh[t4] = bits2f((short)(wv >> 16));
  }
  const float cbl = bits2f((short)(b.cb & 0xffffu));
  const float cbh = bits2f((short)(b.cb >> 16));
  uint32_t xx[19];
#pragma unroll
  for (int j = 0; j < 19; j++) xx[j] = b.x[j];
  if (zero_head && rg == 0) {  // causal left pad at batch starts
    xx[0] = 0;
    xx[1] = 0;
    xx[2] = 0;
  }
#pragma unroll
  for (int j = 0; j < 16; j++) {
    float lo = cbl, hi = cbh;
#pragma unroll
    for (int t4 = 0; t4 < 4; t4++) {
      const uint32_t v = xx[j + t4];
      lo = fmaf(bits2f((short)(v & 0xffffu)), wl[t4], lo);
      hi = fmaf(bits2f((short)(v >> 16)), wh[t4], hi);
    }
    const uint32_t o = ((uint32_t)f2bf(hi) << 16) | f2bf(lo);
    // R9 FIX: XOR row bits 1-2 into bits 4-5 of (colb), not ADD into a base
    // that already contains colb (the add carried into the row bits for
    // colb>=16, scrambling rows -> R8's absmax 43).
    *reinterpret_cast<uint32_t*>(vrow + j * 64 + (colb ^ (((j >> 1) & 3) << 4))) = o;
  }
}

template <int MM, int N, int KD>
__global__ __launch_bounds__(512, 2) void gemm256_conv(
    const bfu* __restrict__ xe, const bfu* __restrict__ Bt,
    const uint32_t* __restrict__ wtab, const float* __restrict__ bias,
    float* __restrict__ Cptr) {
  __shared__ bfu lds[2 * 4 * 8192];  // 128 KiB
  const int t = threadIdx.x;
  const int lane = t & 63, wid = t >> 6;
  const int wr = wid >> 2, wc = wid & 3;
  const int lr = lane & 15, lg = lane >> 4;
  const int cpx = gridDim.x >> 3;
  const int li = (blockIdx.x & 7) * cpx + (blockIdx.x >> 3);
  const int row0 = (li % (MM / 256)) * 256;
  const int col0 = (li / (MM / 256)) * 256;
  constexpr int ntk = KD / 64;
  const int abase = ((wr * 128 + lr) * 64 + lg * 16) ^ (((lr >> 1) & 3) << 4);
  const int bbase = ((wc * 64 + lr) * 64 + lg * 16) ^ (((lr >> 1) & 3) << 4);
  const int rg = lane >> 2;              // 0..15
  const int cp = wid * 4 + (lane & 3);   // 0..31
  const bool zh = (row0 & (L_ - 1)) == 0;

  fx4 acc[8][4] = {};
  Batch bt;

  // -------- prologue: A(0) conv-staged; B(0) both halves + B(1)-kh0; batch(1) pending.
  batch_load(bt, xe, wtab, row0, rg, cp, 0);
  stage_half<KD>(Bt, col0, 0, lds + 16384, t);
  stage_half<KD>(Bt, col0, 32, lds + 24576, t);
  stage_half<KD>(Bt, col0, 64, lds + 32768 + 16384, t);
  conv_write(lds, bt, rg, cp, zh);        // compiler auto-vmcnt for bt
  batch_load(bt, xe, wtab, row0, rg, cp, 1);
  VMW23();  // drain B(0) halves; leave B(1)kh0 + batch(1) in flight
  LGKM0();
  BAR();

  for (int tau = 0; tau < ntk; ++tau) {
    const int cbb = (tau & 1) ? 65536 : 0;
    bfu* nb_ = (tau & 1) ? lds : lds + 32768;
    s16x8 af[4], bf4[4];

    // ---- P1: kh0, m0-3 x n0-3
#pragma unroll
    for (int m = 0; m < 4; m++) af[m] = LF(cbb + abase + m * 1024);
#pragma unroll
    for (int n = 0; n < 4; n++) bf4[n] = LF(cbb + 32768 + bbase + n * 1024);
    BAR();
    LGKM0();
    __builtin_amdgcn_s_setprio(1);
#pragma unroll
    for (int m = 0; m < 4; m++)
#pragma unroll
      for (int n = 0; n < 4; n++)
        acc[m][n] = __builtin_amdgcn_mfma_f32_16x16x32_bf16(af[m], bf4[n], acc[m][n], 0, 0, 0);
    __builtin_amdgcn_s_setprio(0);
    BAR();

    // ---- P2: kh0, m4-7 | stage (tau+1).B-kh1 -> nb_
#pragma unroll
    for (int m = 0; m < 4; m++) af[m] = LF(cbb + abase + 4096 + m * 1024);
    if (tau + 1 < ntk) stage_half<KD>(Bt, col0, (tau + 1) * 64 + 32, nb_ + 24576, t);
    BAR();
    LGKM0();
    __builtin_amdgcn_s_setprio(1);
#pragma unroll
    for (int m = 0; m < 4; m++)
#pragma unroll
      for (int n = 0; n < 4; n++)
        acc[m + 4][n] = __builtin_amdgcn_mfma_f32_16x16x32_bf16(af[m], bf4[n], acc[m + 4][n], 0, 0, 0);
    __builtin_amdgcn_s_setprio(0);
    BAR();

    // ---- P3: kh1, m0-3 x n0-3 | waves 0-3: conv-write A(tau+1)-kh0 -> nb_
#pragma unroll
    for (int m = 0; m < 4; m++) af[m] = LF(cbb + 16384 + abase + m * 1024);
#pragma unroll
    for (int n = 0; n < 4; n++) bf4[n] = LF(cbb + 49152 + bbase + n * 1024);
    BAR();
    if (wid < 4 && tau + 1 < ntk) conv_write(nb_, bt, rg, cp, zh);
    LGKM0();
    __builtin_amdgcn_s_setprio(1);
#pragma unroll
    for (int m = 0; m < 4; m++)
#pragma unroll
      for (int n = 0; n < 4; n++)
        acc[m][n] = __builtin_amdgcn_mfma_f32_16x16x32_bf16(af[m], bf4[n], acc[m][n], 0, 0, 0);
    __builtin_amdgcn_s_setprio(0);
    BAR();

    // ---- P4: kh1, m4-7 | stage (tau+2).B-kh0 | waves 4-7: conv-write A(tau+1)-kh1
    //          then issue batch(tau+2); counted drain
#pragma unroll
    for (int m = 0; m < 4; m++) af[m] = LF(cbb + 16384 + abase + 4096 + m * 1024);
    if (tau + 2 < ntk) stage_half<KD>(Bt, col0, (tau + 2) * 64, lds + (cbb >> 1) + 16384, t);
    BAR();
    if (wid >= 4 && tau + 1 < ntk) conv_write(nb_, bt, rg, cp, zh);
    LGKM0();
    __builtin_amdgcn_s_setprio(1);
#pragma unroll
    for (int m = 0; m < 4; m++)
#pragma unroll
      for (int n = 0; n < 4; n++)
        acc[m + 4][n] = __builtin_amdgcn_mfma_f32_16x16x32_bf16(af[m], bf4[n], acc[m + 4][n], 0, 0, 0);
    __builtin_amdgcn_s_setprio(0);
    if (tau + 2 < ntk) {
      batch_load(bt, xe, wtab, row0, rg, cp, tau + 2);
      // leave batch(tau+2)=21 + B-kh0(tau+2)=2 in flight; drains B-kh1(tau+1)
      // (needed at (tau+1).P3) -- 2 phases old, near-complete.
      VMW23();
    } else {
      VMW0();
    }
    BAR();
  }

  // epilogue
  float bv[4];
#pragma unroll
  for (int n = 0; n < 4; n++) bv[n] = bias[col0 + wc * 64 + n * 16 + lr];
#pragma unroll
  for (int m = 0; m < 8; m++)
#pragma unroll
    for (int n = 0; n < 4; n++)
#pragma unroll
      for (int r = 0; r < 4; r++) {
        const int row = row0 + wr * 128 + m * 16 + lg * 4 + r;
        const int col = col0 + wc * 64 + n * 16 + lr;
        Cptr[(size_t)row * N + col] = acc[m][n][r] + bv[n];
      }
}

extern "C" void kernel_launch(void* const* d_in, const int* in_sizes, int n_in,
                              void* d_out, int out_size, void* d_ws, size_t ws_size,
                              hipStream_t stream) {
  const float* x = (const float*)d_in[0];
  const float* W_exp = (const float*)d_in[1];
  const float* b_exp = (const float*)d_in[2];
  const float* cw = (const float*)d_in[3];
  const float* cb = (const float*)d_in[4];
  const float* W_cmp = (const float*)d_in[5];
  const float* b_cmp = (const float*)d_in[6];
  float* out = (float*)d_out;

  char* ws = (char*)d_ws;
  bfu* wexp_t = (bfu*)(ws);                   // [C][D] bf16, 4 MiB
  bfu* wcmp_t = (bfu*)(ws + (4u << 20));      // [D][C] bf16, 4 MiB
  bfu* xb = (bfu*)(ws + (8u << 20));          // [M][D] bf16, 32 MiB
  bfu* xe = (bfu*)(ws + (40u << 20));         // [M][C] bf16, 64 MiB
  uint32_t* wtab = (uint32_t*)(ws + (104u << 20));  // [1024][8] dwords, 32 KiB

  cvt_f32_bf16<<<2048, 256, 0, stream>>>(x, xb, M_ * D_ / 8);
  transpose_cvt<D_, C_><<<dim3(C_ / 32, D_ / 32), dim3(32, 8), 0, stream>>>(W_exp, wexp_t);
  transpose_cvt<C_, D_><<<dim3(D_ / 32, C_ / 32), dim3(32, 8), 0, stream>>>(W_cmp, wcmp_t);
  prep_cw<<<4, 256, 0, stream>>>(cw, cb, wtab);
  // expand GEMM: xe = x @ W_exp + b_exp
  gemm256<M_, C_, D_, true><<<512, 512, 0, stream>>>(xb, wexp_t, b_exp, xe);
  // fused compress GEMM: out = conv(xe) @ W_cmp + b_cmp   (conv in A-staging)
  gemm256_conv<M_, D_, C_><<<256, 512, 0, stream>>>(xe, wcmp_t, wtab, b_cmp, out);
}